// Round 12
// baseline (148.230 us; speedup 1.0000x reference)
//
#include <hip/hip_runtime.h>
#include <hip/hip_bf16.h>
#include <math.h>

// Problem constants (B=512, D=768, H=256)
#define B 512
#define D 768
#define H 256
#define NN 128          // n = B/4
#define MM 256          // m = B/2
#define P_PAIRS 57280   // sum_{i=0}^{127} (511 - i)
#define NPBLK_P 448     // pair-tiles of 128 (last one half-padded)

typedef _Float16 f16x8 __attribute__((ext_vector_type(8)));
typedef float f32x4 __attribute__((ext_vector_type(4)));

// MFMA 16x16x32 f16:
//   A[m = lane&15][k = (lane>>4)*8 + e]; B from row-major [n][k] same pattern
//   C/D: col = lane&15, row = (lane>>4)*4 + reg
// W2H frag-tile: flat = ((g*8 + s)*64 + lane)*8 + e

static __device__ __forceinline__ f16x8 cvt8(const float* p) {
    float4 a = *(const float4*)p;
    float4 b = *(const float4*)(p + 4);
    f16x8 o;
    o[0] = (_Float16)a.x; o[1] = (_Float16)a.y; o[2] = (_Float16)a.z; o[3] = (_Float16)a.w;
    o[4] = (_Float16)b.x; o[5] = (_Float16)b.y; o[6] = (_Float16)b.z; o[7] = (_Float16)b.w;
    return o;
}

// ---------------- K1: fused norms + uv-GEMM + sim-GEMM + W2H convert ----------------
// blocks [0,256):   uv tile gm = bx>>3 (16 m-rows), nb = bx&7; wave w -> n's [64nb+16w, +16)
// blocks [256,272): sim; wave tile t = (bx-256)*4+w: gm = t>>3 (A rows 16gm<128), slot = t&7
// blocks [272,280): W2H frag-tile conversion
__global__ __launch_bounds__(256) void k_fused(const float* __restrict__ emb,
                                               const float* __restrict__ W1,
                                               const float* __restrict__ W2,
                                               const float* __restrict__ b1,
                                               _Float16* __restrict__ Up,
                                               _Float16* __restrict__ Vv,
                                               _Float16* __restrict__ W2H,
                                               float* __restrict__ esp,   // [8][128]
                                               float* __restrict__ slp) { // [8][128]
    __shared__ float invA[16];
    __shared__ _Float16 Afrag[24 * 64 * 8];  // 24 KB: A-frags for 16 rows x 768 k (raw emb, f16)
    __shared__ float B32[4][16 * 96];        // 24 KB: per-wave fp32 staging (16 rows x 96 k)
    __shared__ float invB[4][64];            // sim: per-wave B-row inverse norms

    int bx = blockIdx.x;
    int tid = threadIdx.x;
    int w = tid >> 6, lane = tid & 63;
    int r = lane & 15, q = lane >> 4;

    if (bx >= 272) {
        // ---- W2H riders: 8 blocks x 1024 units over 16g x 8s x 64lc ----
        int rel = bx - 272;
        #pragma unroll
        for (int it = 0; it < 4; it++) {
            int u = rel * 1024 + it * 256 + tid;     // 0..8191
            int g = u >> 9, s = (u >> 6) & 7, lc = u & 63;
            const float* src = W2 + (16 * g + (lc & 15)) * H + 32 * s + 8 * (lc >> 4);
            *(f16x8*)(W2H + ((g * 8 + s) * 64 + lc) * 8) = cvt8(src);
        }
        return;
    }

    bool is_sim = (bx >= 256);
    int gm = is_sim ? ((bx - 256) >> 1) : (bx >> 3);

    // ---- Phase A1: inverse norms of the 16 A-rows (coalesced-per-thread) ----
    {
        int row = tid >> 4, seg = tid & 15;
        const float4* rp = (const float4*)(emb + (16 * gm + row) * D) + seg * 12;
        float ss = 0.f;
        #pragma unroll
        for (int j = 0; j < 12; j++) {
            float4 v = rp[j];
            ss += v.x * v.x + v.y * v.y + v.z * v.z + v.w * v.w;
        }
        #pragma unroll
        for (int m = 1; m <= 8; m <<= 1) ss += __shfl_xor(ss, m);
        if (seg == 0) invA[row] = 1.0f / fmaxf(sqrtf(ss), 1e-12f);
    }

    // ---- Phase A2: build A-frags from raw emb (f16, unscaled) ----
    #pragma unroll
    for (int it = 0; it < 6; it++) {
        int u = it * 256 + tid;                      // 0..1535 = 24 s x 64 lanes
        int s = u >> 6, lc = u & 63;
        const float* src = emb + (16 * gm + (lc & 15)) * D + 32 * s + 8 * (lc >> 4);
        *(f16x8*)&Afrag[(s * 64 + lc) * 8] = cvt8(src);
    }
    __syncthreads();

    if (!is_sim) {
        // ================= uv: wave computes 16m x 16n, K=768 =================
        int nb = bx & 7;
        int n0 = 64 * nb + 16 * w;                   // wave's n-range [n0, n0+16)
        f32x4 acc = {};
        float* myB = &B32[w][0];

        for (int c = 0; c < 8; c++) {
            // stage W1 rows [n0, n0+16), k-chunk [96c, 96c+96) -> fp32 LDS (coalesced)
            #pragma unroll
            for (int it = 0; it < 6; it++) {
                int f = it * 64 + lane;              // 0..383
                int rr = f / 24, c4 = f % 24;
                int n = n0 + rr;
                const float* src = W1 + (n & 255) * (2 * D) + (n >> 8) * D + 96 * c + 4 * c4;
                *(float4*)&myB[rr * 96 + 4 * c4] = *(const float4*)src;
            }
            // 3 MFMA steps from staged chunk (B-frag converted in-register)
            #pragma unroll
            for (int s2 = 0; s2 < 3; s2++) {
                int s = 3 * c + s2;
                f16x8 bf = cvt8(&myB[r * 96 + 32 * s2 + 8 * q]);
                f16x8 a = *(const f16x8*)&Afrag[(s * 64 + lane) * 8];
                acc = __builtin_amdgcn_mfma_f32_16x16x32_f16(a, bf, acc, 0, 0, 0);
            }
        }

        // epilogue: post-scale by inv_m, add b1, store f16
        int n = n0 + r;
        float bias = (n < H) ? b1[n] : 0.f;
        #pragma unroll
        for (int rr = 0; rr < 4; rr++) {
            int m = 16 * gm + 4 * q + rr;
            float val = acc[rr] * invA[4 * q + rr] + bias;
            if (n < H) Up[m * H + n] = (_Float16)val;
            else       Vv[m * H + (n - H)] = (_Float16)val;
        }
    } else {
        // ================= sim: wave computes 16i x 64k, K=768 =================
        int t = (bx - 256) * 4 + w;                  // 0..63
        int slot = t & 7;                            // B-cols [64*slot, +64)
        float* myB = &B32[w][0];

        // B-row inverse norms (64 rows), 4-lane groups per row
        #pragma unroll
        for (int p = 0; p < 4; p++) {
            int rowrel = 16 * p + (lane >> 2);
            const float* rb = emb + (64 * slot + rowrel) * D;
            float ss = 0.f;
            #pragma unroll 8
            for (int it = 0; it < 48; it++) {
                float4 v = *(const float4*)(rb + 4 * ((lane & 3) + 4 * it));
                ss += v.x * v.x + v.y * v.y + v.z * v.z + v.w * v.w;
            }
            ss += __shfl_xor(ss, 1);
            ss += __shfl_xor(ss, 2);
            if ((lane & 3) == 0) invB[w][rowrel] = 1.0f / fmaxf(sqrtf(ss), 1e-12f);
        }

        f32x4 acc[4] = {};
        for (int c = 0; c < 8; c++) {
            #pragma unroll
            for (int nt = 0; nt < 4; nt++) {
                // stage emb rows [64slot+16nt, +16), k-chunk [96c,+96)
                #pragma unroll
                for (int it = 0; it < 6; it++) {
                    int f = it * 64 + lane;
                    int rr = f / 24, c4 = f % 24;
                    const float* src = emb + (64 * slot + 16 * nt + rr) * D + 96 * c + 4 * c4;
                    *(float4*)&myB[rr * 96 + 4 * c4] = *(const float4*)src;
                }
                #pragma unroll
                for (int s2 = 0; s2 < 3; s2++) {
                    int s = 3 * c + s2;
                    f16x8 bf = cvt8(&myB[r * 96 + 32 * s2 + 8 * q]);
                    f16x8 a = *(const f16x8*)&Afrag[(s * 64 + lane) * 8];
                    acc[nt] = __builtin_amdgcn_mfma_f32_16x16x32_f16(a, bf, acc[nt], 0, 0, 0);
                }
            }
        }

        // epilogue: S = C * inv_i * inv_k; accumulate expsum / slog partials
        #pragma unroll
        for (int rr = 0; rr < 4; rr++) {
            int irow = 16 * gm + 4 * q + rr;
            float ia = invA[4 * q + rr];
            float es = 0.f, sl = 0.f;
            #pragma unroll
            for (int nt = 0; nt < 4; nt++) {
                int kcol = 64 * slot + 16 * nt + r;
                float S = acc[nt][rr] * ia * invB[w][16 * nt + r];
                if (kcol != irow) es += expf(2.f * S);
                if (kcol > irow && kcol < NN) sl += 2.f * S;
            }
            #pragma unroll
            for (int m = 1; m <= 8; m <<= 1) {
                es += __shfl_xor(es, m);
                sl += __shfl_xor(sl, m);
            }
            if (r == 0) {
                esp[slot * NN + irow] = es;
                slp[slot * NN + irow] = sl;
            }
        }
    }
}

// ---------------- K2: pair MLP (448 x 128-pair tiles) ----------------
__global__ __launch_bounds__(256, 2) void k_pairs(const _Float16* __restrict__ Up,
                                                  const _Float16* __restrict__ Vv,
                                                  const _Float16* __restrict__ W2H,
                                                  const float* __restrict__ b2,
                                                  const float* __restrict__ W3,
                                                  const float* __restrict__ b3,
                                                  float* __restrict__ bcepart) {
    __shared__ _Float16 h1[128][264];    // 66 KB
    __shared__ float redbuf[4][128];
    __shared__ float red2[2];

    int tid = threadIdx.x;
    int w = tid >> 6, lane = tid & 63;
    int r = lane & 15, q = lane >> 4;
    int bx = blockIdx.x;
    int p0 = bx * 128;

    // stage h1 = relu(U'[i] + V[j]) f16; (i,j) computed inline per unit
    #pragma unroll
    for (int uu = 0; uu < 2; uu++) {
        int u = uu * 256 + tid;              // 0..511
        int row = u >> 2, cq = u & 3;
        int p = p0 + row;
        if (p >= P_PAIRS) p = P_PAIRS - 1;   // pad rows duplicate last pair (masked later)
        float disc = 1046529.f - 8.f * (float)p;   // 1023^2 - 8p, exact in fp32
        int i = (int)((1023.f - sqrtf(disc)) * 0.5f);
        if (i < 0) i = 0;
        if (i > NN - 1) i = NN - 1;
        while (i > 0 && i * (1023 - i) / 2 > p) i--;
        while ((i + 1) * (1022 - i) / 2 <= p) i++;
        int j = i + 1 + (p - i * (1023 - i) / 2);

        const _Float16* up = Up + i * H + 64 * cq;
        const _Float16* vp = Vv + j * H + 64 * cq;
        #pragma unroll
        for (int c8 = 0; c8 < 8; c8++) {
            f16x8 u8 = *(const f16x8*)(up + 8 * c8);
            f16x8 v8 = *(const f16x8*)(vp + 8 * c8);
            f16x8 zero = {};
            f16x8 hv = __builtin_elementwise_max(u8 + v8, zero);
            *(f16x8*)&h1[row][64 * cq + 8 * c8] = hv;
        }
    }
    __syncthreads();

    // MFMA: C[128 pairs][64 cols per wave] = h1 @ W2^T
    f32x4 acc[8][4] = {};                    // [mt][nt]
    #pragma unroll
    for (int s = 0; s < 8; s++) {
        f16x8 bb[4];
        #pragma unroll
        for (int nt = 0; nt < 4; nt++)
            bb[nt] = *(const f16x8*)(W2H + (((4 * w + nt) * 8 + s) * 64 + lane) * 8);
        #pragma unroll
        for (int mt = 0; mt < 8; mt++) {
            f16x8 a = *(const f16x8*)&h1[16 * mt + r][32 * s + 8 * q];
            #pragma unroll
            for (int nt = 0; nt < 4; nt++)
                acc[mt][nt] = __builtin_amdgcn_mfma_f32_16x16x32_f16(a, bb[nt], acc[mt][nt], 0, 0, 0);
        }
    }

    // epilogue: h2 = relu(C + b2), partial logit = sum_n h2*W3
    float b2v[4], w3v[4];
    #pragma unroll
    for (int nt = 0; nt < 4; nt++) {
        int n = 64 * w + 16 * nt + r;
        b2v[nt] = b2[n];
        w3v[nt] = W3[n];
    }
    #pragma unroll
    for (int mt = 0; mt < 8; mt++) {
        float part[4] = {0.f, 0.f, 0.f, 0.f};
        #pragma unroll
        for (int nt = 0; nt < 4; nt++)
            #pragma unroll
            for (int rr = 0; rr < 4; rr++) {
                float h2 = fmaxf(acc[mt][nt][rr] + b2v[nt], 0.f);
                part[rr] += h2 * w3v[nt];
            }
        #pragma unroll
        for (int rr = 0; rr < 4; rr++) {
            float v = part[rr];
            #pragma unroll
            for (int m = 1; m <= 8; m <<= 1) v += __shfl_xor(v, m);
            if (r == 0) redbuf[w][16 * mt + 4 * q + rr] = v;
        }
    }
    __syncthreads();

    if (tid < 128) {
        int p = p0 + tid;
        float lsum = 0.f;
        if (p < P_PAIRS) {
            float disc = 1046529.f - 8.f * (float)p;
            int i = (int)((1023.f - sqrtf(disc)) * 0.5f);
            if (i < 0) i = 0;
            if (i > NN - 1) i = NN - 1;
            while (i > 0 && i * (1023 - i) / 2 > p) i--;
            while ((i + 1) * (1022 - i) / 2 <= p) i++;
            int j = i + 1 + (p - i * (1023 - i) / 2);

            float logit = redbuf[0][tid] + redbuf[1][tid] +
                          redbuf[2][tid] + redbuf[3][tid] + b3[0];
            float label = (j < MM) ? 1.f : 0.f;
            lsum = fmaxf(logit, 0.f) - logit * label + log1pf(expf(-fabsf(logit)));
        }
        #pragma unroll
        for (int off = 32; off > 0; off >>= 1) lsum += __shfl_down(lsum, off);
        if ((tid & 63) == 0) red2[tid >> 6] = lsum;
    }
    __syncthreads();
    if (tid == 0) bcepart[bx] = red2[0] + red2[1];   // plain store, no atomic/fence
}

// ---------------- K3: final combine ----------------
__global__ __launch_bounds__(256) void k_final(const float* __restrict__ esp,
                                               const float* __restrict__ slp,
                                               const float* __restrict__ bcepart,
                                               float* __restrict__ out) {
    __shared__ float red[256];
    int t = threadIdx.x;

    float s = 0.f;
    for (int p = t; p < NPBLK_P; p += 256) s += bcepart[p];
    red[t] = s;
    __syncthreads();
    for (int st = 128; st > 0; st >>= 1) {
        if (t < st) red[t] += red[t + st];
        __syncthreads();
    }
    float bce_total = red[0];
    __syncthreads();

    float v = 0.f;
    if (t < NN) {
        float es = 0.f, sl = 0.f;
        #pragma unroll
        for (int s8 = 0; s8 < 8; s8++) {
            es += esp[s8 * NN + t];
            sl += slp[s8 * NN + t];
        }
        v = (float)(NN - 1 - t) * logf(es) - sl;
    }
    red[t] = v;
    __syncthreads();
    for (int st = 128; st > 0; st >>= 1) {
        if (t < st) red[t] += red[t + st];
        __syncthreads();
    }
    if (t == 0) {
        float closs = (-2.0f * (float)(NN - 1) / (float)NN) * red[0];
        out[0] = closs + bce_total / (float)P_PAIRS;
    }
}

extern "C" void kernel_launch(void* const* d_in, const int* in_sizes, int n_in,
                              void* d_out, int out_size, void* d_ws, size_t ws_size,
                              hipStream_t stream) {
    const float* emb = (const float*)d_in[0];
    const float* W1  = (const float*)d_in[1];
    const float* b1  = (const float*)d_in[2];
    const float* W2  = (const float*)d_in[3];
    const float* b2  = (const float*)d_in[4];
    const float* W3  = (const float*)d_in[5];
    const float* b3  = (const float*)d_in[6];
    float* out = (float*)d_out;

    float* ws = (float*)d_ws;
    float* esp     = ws;                         // 8*128
    float* slp     = ws + 1024;                  // 8*128
    float* bcepart = ws + 2048;                  // 448
    _Float16* W2H = (_Float16*)(ws + 3072);      // 256*256 frag-tiled
    _Float16* Up  = W2H + H * H;                 // 512*256 row-major f16
    _Float16* Vv  = Up + B * H;                  // 512*256 row-major f16

    k_fused<<<280, 256, 0, stream>>>(emb, W1, W2, b1, Up, Vv, W2H, esp, slp);
    k_pairs<<<NPBLK_P, 256, 0, stream>>>(Up, Vv, W2H, b2, W3, b3, bcepart);
    k_final<<<1, 256, 0, stream>>>(esp, slp, bcepart, out);
}

// Round 13
// 100.034 us; speedup vs baseline: 1.4818x; 1.4818x over previous
//
#include <hip/hip_runtime.h>
#include <hip/hip_bf16.h>
#include <math.h>

// Problem constants (B=512, D=768, H=256)
#define B 512
#define D 768
#define H 256
#define NN 128          // n = B/4
#define MM 256          // m = B/2
#define P_PAIRS 57280   // sum_{i=0}^{127} (511 - i)
#define NPBLK_P 448     // pair-tiles of 128 (last one half-padded)

typedef _Float16 f16x8 __attribute__((ext_vector_type(8)));
typedef float f32x4 __attribute__((ext_vector_type(4)));

// MFMA 16x16x32 f16:
//   A[m = lane&15][k = (lane>>4)*8 + e]; B from row-major [n][k] same pattern
//   C/D: col = lane&15, row = (lane>>4)*4 + reg
// Frag-tile layout: flat = ((g*S + s)*64 + lane)*8 + e  <=>  M[16g + (lane&15)][32s + (lane>>4)*8 + e]
//
// Structure note (R12 post-mortem): this 4-kernel chain at ~101 µs beat every
// structural alternative tried: cooperative mega-kernel (launch fails), direct
// raw-emb gather GEMM (40 µs uvsim, latency-bound), fused LDS-staged GEMM
// (65 µs, 5.3M LDS bank conflicts from 96-float stride ≡ 0 mod 32). Device-scope
// fences/tickets in wide kernels cost ~10 µs (R4, R10) — keep plain stores +
// separate tiny combine kernel.

// ---------------- K0: prep, 160 blocks ----------------
// blocks [0,64):    z rows [8bx, 8bx+8) -> norms + zH frag-tiles
// blocks [64,128):  W1H frag-tiles (group (bx-64)>>1, s-half (bx-64)&1)
// blocks [128,160): W2H frag-tiles (group (bx-128)>>1, s-half (bx-128)&1)
__global__ __launch_bounds__(256) void k_prep(const float* __restrict__ emb,
                                              const float* __restrict__ W1,
                                              const float* __restrict__ W2,
                                              _Float16* __restrict__ zH,
                                              _Float16* __restrict__ W1H,
                                              _Float16* __restrict__ W2H) {
    __shared__ float invs[8];
    int bx = blockIdx.x;
    int tid = threadIdx.x;
    int w = tid >> 6, lane = tid & 63;

    if (bx < 64) {
        int g8 = bx;                    // 8-row block
        int grp = g8 >> 1;              // frag group 0..31
        int h = g8 & 1;                 // row half within group
        // phase 1: norms (wave w -> rows 2w, 2w+1)
        #pragma unroll
        for (int rr = 0; rr < 2; rr++) {
            int r8 = 2 * w + rr;        // 0..7
            const float* rp = emb + (8 * g8 + r8) * D;
            float ss = 0.f;
            #pragma unroll
            for (int it = 0; it < 12; it++) {
                float v = rp[lane + 64 * it];
                ss += v * v;
            }
            #pragma unroll
            for (int m = 1; m <= 32; m <<= 1) ss += __shfl_xor(ss, m);
            if (lane == 0) invs[r8] = 1.0f / fmaxf(sqrtf(ss), 1e-12f);
        }
        __syncthreads();
        // phase 2: 768 chunks = 24 s x 4 q x 8 r8
        #pragma unroll
        for (int it = 0; it < 3; it++) {
            int chunk = it * 256 + tid;
            int s = chunk >> 5;
            int x = chunk & 31;
            int q = x >> 3, r8 = x & 7;
            int r = h * 8 + r8;
            const float* src = emb + (8 * g8 + r8) * D + 32 * s + 8 * q;
            float inv = invs[r8];
            float4 a = *(const float4*)src;
            float4 bb = *(const float4*)(src + 4);
            f16x8 o;
            o[0] = (_Float16)(a.x * inv); o[1] = (_Float16)(a.y * inv);
            o[2] = (_Float16)(a.z * inv); o[3] = (_Float16)(a.w * inv);
            o[4] = (_Float16)(bb.x * inv); o[5] = (_Float16)(bb.y * inv);
            o[6] = (_Float16)(bb.z * inv); o[7] = (_Float16)(bb.w * inv);
            *(f16x8*)(zH + ((grp * 24 + s) * 64 + q * 16 + r) * 8) = o;
        }
    } else if (bx < 128) {
        // W1H: row n = 16g+r reads W1[n&255][(n>>8)*768 + k]
        int g = (bx - 64) >> 1;
        int sh = (bx - 64) & 1;
        #pragma unroll
        for (int it = 0; it < 3; it++) {
            int chunk = it * 256 + tid;          // 0..767
            int s = sh * 12 + (chunk >> 6);
            int lc = chunk & 63;
            int q = lc >> 4, r = lc & 15;
            int n = 16 * g + r;
            const float* src = W1 + (n & 255) * (2 * D) + (n >> 8) * D + 32 * s + 8 * q;
            float4 a = *(const float4*)src;
            float4 bb = *(const float4*)(src + 4);
            f16x8 o;
            o[0] = (_Float16)a.x; o[1] = (_Float16)a.y; o[2] = (_Float16)a.z; o[3] = (_Float16)a.w;
            o[4] = (_Float16)bb.x; o[5] = (_Float16)bb.y; o[6] = (_Float16)bb.z; o[7] = (_Float16)bb.w;
            *(f16x8*)(W1H + ((g * 24 + s) * 64 + lc) * 8) = o;
        }
    } else {
        // W2H: group g, s-half sh; 256 chunks = 4 s x 64 lc
        int g = (bx - 128) >> 1;
        int sh = (bx - 128) & 1;
        int s = sh * 4 + (tid >> 6);
        int lc = tid & 63;
        int q = lc >> 4, r = lc & 15;
        const float* src = W2 + (16 * g + r) * H + 32 * s + 8 * q;
        float4 a = *(const float4*)src;
        float4 bb = *(const float4*)(src + 4);
        f16x8 o;
        o[0] = (_Float16)a.x; o[1] = (_Float16)a.y; o[2] = (_Float16)a.z; o[3] = (_Float16)a.w;
        o[4] = (_Float16)bb.x; o[5] = (_Float16)bb.y; o[6] = (_Float16)bb.z; o[7] = (_Float16)bb.w;
        *(f16x8*)(W2H + ((g * 8 + s) * 64 + lc) * 8) = o;
    }
}

// ---------------- K1: uv, 256 blocks x 128 threads (2 wave-tiles per block) ----------------
__global__ __launch_bounds__(128) void k_uv(const _Float16* __restrict__ zH,
                                            const _Float16* __restrict__ W1H,
                                            const float* __restrict__ b1,
                                            _Float16* __restrict__ Up,
                                            _Float16* __restrict__ Vv) {
    int w = threadIdx.x >> 6;
    int lane = threadIdx.x & 63;
    int r = lane & 15, q = lane >> 4;
    int gid = blockIdx.x * 2 + w;            // 0..511
    int gm = gid >> 4;                       // 0..31
    int gnp = gid & 15;                      // n-tile pair

    f32x4 acc[2] = {};
    #pragma unroll 4
    for (int s = 0; s < 24; s++) {
        f16x8 a = *(const f16x8*)(zH + ((gm * 24 + s) * 64 + lane) * 8);
        #pragma unroll
        for (int nt = 0; nt < 2; nt++) {
            f16x8 bb = *(const f16x8*)(W1H + (((gnp * 2 + nt) * 24 + s) * 64 + lane) * 8);
            acc[nt] = __builtin_amdgcn_mfma_f32_16x16x32_f16(a, bb, acc[nt], 0, 0, 0);
        }
    }
    #pragma unroll
    for (int nt = 0; nt < 2; nt++) {
        int n = (gnp * 2 + nt) * 16 + r;
        float bias = (n < H) ? b1[n] : 0.f;
        #pragma unroll
        for (int rr = 0; rr < 4; rr++) {
            int m = gm * 16 + 4 * q + rr;
            float C = acc[nt][rr] + bias;
            if (n < H) Up[m * H + n] = (_Float16)C;
            else       Vv[m * H + (n - H)] = (_Float16)C;
        }
    }
}

// ---------------- K2: pair MLP (448 x 128-pair tiles) + sim rides in blocks [448,464) ----------------
__global__ __launch_bounds__(256, 2) void k_pairs(const _Float16* __restrict__ Up,
                                                  const _Float16* __restrict__ Vv,
                                                  const _Float16* __restrict__ W2H,
                                                  const _Float16* __restrict__ zH,
                                                  const float* __restrict__ b2,
                                                  const float* __restrict__ W3,
                                                  const float* __restrict__ b3,
                                                  float* __restrict__ bcepart,
                                                  float* __restrict__ esp,   // [8][128]
                                                  float* __restrict__ slp) { // [8][128]
    int tid = threadIdx.x;
    int w = tid >> 6, lane = tid & 63;
    int r = lane & 15, q = lane >> 4;
    int bx = blockIdx.x;

    if (bx >= NPBLK_P) {
        // ---- similarity stats: wave tile t = (bx-448)*4+w ----
        int t = (bx - NPBLK_P) * 4 + w;      // 0..63
        int gm = t >> 3;                     // rows < 128
        int slot = t & 7;
        int gn0 = slot * 4;
        f32x4 acc[4] = {};
        #pragma unroll 4
        for (int s = 0; s < 24; s++) {
            f16x8 a = *(const f16x8*)(zH + ((gm * 24 + s) * 64 + lane) * 8);
            #pragma unroll
            for (int nt = 0; nt < 4; nt++) {
                f16x8 bb = *(const f16x8*)(zH + (((gn0 + nt) * 24 + s) * 64 + lane) * 8);
                acc[nt] = __builtin_amdgcn_mfma_f32_16x16x32_f16(a, bb, acc[nt], 0, 0, 0);
            }
        }
        #pragma unroll
        for (int rr = 0; rr < 4; rr++) {
            int irow = gm * 16 + q * 4 + rr;
            float es = 0.f, sl = 0.f;
            #pragma unroll
            for (int nt = 0; nt < 4; nt++) {
                int kcol = (gn0 + nt) * 16 + r;
                float C = acc[nt][rr];
                if (kcol != irow) es += expf(2.f * C);
                if (kcol > irow && kcol < NN) sl += 2.f * C;
            }
            #pragma unroll
            for (int m = 1; m <= 8; m <<= 1) {
                es += __shfl_xor(es, m);
                sl += __shfl_xor(sl, m);
            }
            if (r == 0) {
                esp[slot * NN + irow] = es;
                slp[slot * NN + irow] = sl;
            }
        }
        return;
    }

    // ---- pair blocks ----
    __shared__ _Float16 h1[128][264];    // 66 KB
    __shared__ float redbuf[4][128];
    __shared__ float red2[2];

    int p0 = bx * 128;

    // stage h1 = relu(U'[i] + V[j]) f16; (i,j) computed inline per unit (no barrier)
    #pragma unroll
    for (int uu = 0; uu < 2; uu++) {
        int u = uu * 256 + tid;              // 0..511
        int row = u >> 2, cq = u & 3;
        int p = p0 + row;
        if (p >= P_PAIRS) p = P_PAIRS - 1;   // pad rows duplicate last pair (masked later)
        float disc = 1046529.f - 8.f * (float)p;   // 1023^2 - 8p, exact in fp32
        int i = (int)((1023.f - sqrtf(disc)) * 0.5f);
        if (i < 0) i = 0;
        if (i > NN - 1) i = NN - 1;
        while (i > 0 && i * (1023 - i) / 2 > p) i--;
        while ((i + 1) * (1022 - i) / 2 <= p) i++;
        int j = i + 1 + (p - i * (1023 - i) / 2);

        const _Float16* up = Up + i * H + 64 * cq;
        const _Float16* vp = Vv + j * H + 64 * cq;
        #pragma unroll
        for (int c8 = 0; c8 < 8; c8++) {
            f16x8 u8 = *(const f16x8*)(up + 8 * c8);
            f16x8 v8 = *(const f16x8*)(vp + 8 * c8);
            f16x8 zero = {};
            f16x8 hv = __builtin_elementwise_max(u8 + v8, zero);
            *(f16x8*)&h1[row][64 * cq + 8 * c8] = hv;
        }
    }
    __syncthreads();

    // MFMA: C[128 pairs][64 cols per wave] = h1 @ W2^T
    f32x4 acc[8][4] = {};                    // [mt][nt]
    #pragma unroll
    for (int s = 0; s < 8; s++) {
        f16x8 bb[4];
        #pragma unroll
        for (int nt = 0; nt < 4; nt++)
            bb[nt] = *(const f16x8*)(W2H + (((4 * w + nt) * 8 + s) * 64 + lane) * 8);
        #pragma unroll
        for (int mt = 0; mt < 8; mt++) {
            f16x8 a = *(const f16x8*)&h1[16 * mt + r][32 * s + 8 * q];
            #pragma unroll
            for (int nt = 0; nt < 4; nt++)
                acc[mt][nt] = __builtin_amdgcn_mfma_f32_16x16x32_f16(a, bb[nt], acc[mt][nt], 0, 0, 0);
        }
    }

    // epilogue: h2 = relu(C + b2), partial logit = sum_n h2*W3
    float b2v[4], w3v[4];
    #pragma unroll
    for (int nt = 0; nt < 4; nt++) {
        int n = 64 * w + 16 * nt + r;
        b2v[nt] = b2[n];
        w3v[nt] = W3[n];
    }
    #pragma unroll
    for (int mt = 0; mt < 8; mt++) {
        float part[4] = {0.f, 0.f, 0.f, 0.f};
        #pragma unroll
        for (int nt = 0; nt < 4; nt++)
            #pragma unroll
            for (int rr = 0; rr < 4; rr++) {
                float h2 = fmaxf(acc[mt][nt][rr] + b2v[nt], 0.f);
                part[rr] += h2 * w3v[nt];
            }
        #pragma unroll
        for (int rr = 0; rr < 4; rr++) {
            float v = part[rr];
            #pragma unroll
            for (int m = 1; m <= 8; m <<= 1) v += __shfl_xor(v, m);
            if (r == 0) redbuf[w][16 * mt + 4 * q + rr] = v;
        }
    }
    __syncthreads();

    if (tid < 128) {
        int p = p0 + tid;
        float lsum = 0.f;
        if (p < P_PAIRS) {
            // recompute j for label
            float disc = 1046529.f - 8.f * (float)p;
            int i = (int)((1023.f - sqrtf(disc)) * 0.5f);
            if (i < 0) i = 0;
            if (i > NN - 1) i = NN - 1;
            while (i > 0 && i * (1023 - i) / 2 > p) i--;
            while ((i + 1) * (1022 - i) / 2 <= p) i++;
            int j = i + 1 + (p - i * (1023 - i) / 2);

            float logit = redbuf[0][tid] + redbuf[1][tid] +
                          redbuf[2][tid] + redbuf[3][tid] + b3[0];
            float label = (j < MM) ? 1.f : 0.f;
            lsum = fmaxf(logit, 0.f) - logit * label + log1pf(expf(-fabsf(logit)));
        }
        #pragma unroll
        for (int off = 32; off > 0; off >>= 1) lsum += __shfl_down(lsum, off);
        if ((tid & 63) == 0) red2[tid >> 6] = lsum;
    }
    __syncthreads();
    if (tid == 0) bcepart[bx] = red2[0] + red2[1];   // plain store, no atomic/fence
}

// ---------------- K3: final combine ----------------
__global__ __launch_bounds__(256) void k_final(const float* __restrict__ esp,
                                               const float* __restrict__ slp,
                                               const float* __restrict__ bcepart,
                                               float* __restrict__ out) {
    __shared__ float red[256];
    int t = threadIdx.x;

    float s = 0.f;
    for (int p = t; p < NPBLK_P; p += 256) s += bcepart[p];
    red[t] = s;
    __syncthreads();
    for (int st = 128; st > 0; st >>= 1) {
        if (t < st) red[t] += red[t + st];
        __syncthreads();
    }
    float bce_total = red[0];
    __syncthreads();

    float v = 0.f;
    if (t < NN) {
        float es = 0.f, sl = 0.f;
        #pragma unroll
        for (int s8 = 0; s8 < 8; s8++) {
            es += esp[s8 * NN + t];
            sl += slp[s8 * NN + t];
        }
        v = (float)(NN - 1 - t) * logf(es) - sl;
    }
    red[t] = v;
    __syncthreads();
    for (int st = 128; st > 0; st >>= 1) {
        if (t < st) red[t] += red[t + st];
        __syncthreads();
    }
    if (t == 0) {
        float closs = (-2.0f * (float)(NN - 1) / (float)NN) * red[0];
        out[0] = closs + bce_total / (float)P_PAIRS;
    }
}

extern "C" void kernel_launch(void* const* d_in, const int* in_sizes, int n_in,
                              void* d_out, int out_size, void* d_ws, size_t ws_size,
                              hipStream_t stream) {
    const float* emb = (const float*)d_in[0];
    const float* W1  = (const float*)d_in[1];
    const float* b1  = (const float*)d_in[2];
    const float* W2  = (const float*)d_in[3];
    const float* b2  = (const float*)d_in[4];
    const float* W3  = (const float*)d_in[5];
    const float* b3  = (const float*)d_in[6];
    float* out = (float*)d_out;

    float* ws = (float*)d_ws;
    float* esp     = ws;                         // 8*128
    float* slp     = ws + 1024;                  // 8*128
    float* bcepart = ws + 2048;                  // 448
    _Float16* zH  = (_Float16*)(ws + 3072);      // 512*768 frag-tiled
    _Float16* W1H = zH + B * D;                  // 512*768 frag-tiled
    _Float16* W2H = W1H + 2 * H * D;             // 256*256 frag-tiled
    _Float16* Up  = W2H + H * H;                 // 512*256 row-major
    _Float16* Vv  = Up + B * H;                  // 512*256 row-major

    k_prep<<<160, 256, 0, stream>>>(emb, W1, W2, zH, W1H, W2H);
    k_uv<<<256, 128, 0, stream>>>(zH, W1H, b1, Up, Vv);
    k_pairs<<<NPBLK_P + 16, 256, 0, stream>>>(Up, Vv, W2H, zH, b2, W3, b3,
                                              bcepart, esp, slp);
    k_final<<<1, 256, 0, stream>>>(esp, slp, bcepart, out);
}